// Round 7
// baseline (161.595 us; speedup 1.0000x reference)
//
#include <hip/hip_runtime.h>

// Problem constants: x [32,64,64,64] f32, embed [64,512] f32.
#define N_VEC 131072
#define D 64
#define K 512
#define GUARD 0.08f      // >= 6x worst-case coarse-score error bound
#define NB_GATHER 2048

typedef __attribute__((ext_vector_type(8))) short bf16x8;  // 8 bf16 = 4 VGPR
typedef __attribute__((ext_vector_type(4))) float f32x4;

static __device__ __forceinline__ short f2bf(float f) {   // RNE
  unsigned u = __builtin_bit_cast(unsigned, f);
  u += 0x7fffu + ((u >> 16) & 1u);
  return (short)(u >> 16);
}
static __device__ __forceinline__ float bf2f(short h) {
  unsigned u = ((unsigned)(unsigned short)h) << 16;
  return __builtin_bit_cast(float, u);
}
static __device__ __forceinline__ void split8(const float4 f0, const float4 f1,
                                              bf16x8& h, bf16x8& m) {
  const float v[8] = {f0.x, f0.y, f0.z, f0.w, f1.x, f1.y, f1.z, f1.w};
#pragma unroll
  for (int j = 0; j < 8; ++j) {
    const short hh = f2bf(v[j]);
    h[j] = hh;
    m[j] = f2bf(v[j] - bf2f(hh));
  }
}

// ---------------------------------------------------------------------------
// Prep (grid 40 x 64):
//   blocks 0-31:  pack codebook hi/mid bf16 B-fragments (tile b) into F in
//                 MFMA fragment order: F[t*256 + c*128 + s*64 + lane].
//   blocks 32-39: et[k][d] fp32 transpose + nrm (fma order d ascending, same
//                 as rounds 1-6 -> bit-identical) + flag-counter zeroing.
// ---------------------------------------------------------------------------
__global__ __launch_bounds__(64) void vq_prep_kernel(
    const float* __restrict__ embed, float* __restrict__ et,
    float* __restrict__ nrm, bf16x8* __restrict__ F, int* __restrict__ cnt)
{
  const int b = blockIdx.x;
  const int lane = threadIdx.x;
  if (b < 32) {
    const int row = lane & 15;   // code within tile
    const int kg  = lane >> 4;   // dim-group
    const int code = b * 16 + row;
#pragma unroll
    for (int c = 0; c < 2; ++c) {
      bf16x8 h, m;
#pragma unroll
      for (int j = 0; j < 8; ++j) {
        const int d = kg * 8 + c * 32 + j;
        const float e = embed[d * K + code];
        const short hh = f2bf(e);
        h[j] = hh;
        m[j] = f2bf(e - bf2f(hh));
      }
      F[b * 256 + c * 128 + 0  + lane] = h;
      F[b * 256 + c * 128 + 64 + lane] = m;
    }
  } else {
    if (b == 32 && lane == 0) cnt[0] = 0;
    const int code = (b - 32) * 64 + lane;     // 0..511
    float s = 0.f;
#pragma unroll
    for (int d = 0; d < D; ++d) {
      const float e = embed[d * K + code];
      et[code * D + d] = e;
      s = fmaf(e, e, s);
    }
    nrm[code] = s;
  }
}

// ---------------------------------------------------------------------------
// Coarse: wave = 32 queries (two 16-row A-sets, hi/mid bf16), streams 32
// code-tiles of 16 via pre-packed B-frags. 12 MFMA/tile. Per lane: 8
// best/2nd/idx triples. gap<GUARD -> query index appended to compact list.
// Scoring numerics identical to rounds 5/6 (passed).
// ---------------------------------------------------------------------------
__global__ __launch_bounds__(256, 4) void vq_coarse_kernel(
    const float* __restrict__ x, const bf16x8* __restrict__ F,
    const float* __restrict__ nrm, float* __restrict__ idf,
    int* __restrict__ cnt, int* __restrict__ list)
{
  const int tid  = threadIdx.x;
  const int lane = tid & 63;
  const int wid  = blockIdx.x * 4 + (tid >> 6);
  const int qbase = wid * 32;
  const int row = lane & 15;
  const int kg  = lane >> 4;

  // Build A fragments (2 query-sets x 2 K-chunks, hi+mid).
  bf16x8 Ah0c0, Ah0c1, Ah1c0, Ah1c1, Am0c0, Am0c1, Am1c0, Am1c1;
  {
    const float* xr0 = x + (size_t)(qbase + row) * D + kg * 8;
    const float* xr1 = x + (size_t)(qbase + 16 + row) * D + kg * 8;
    split8(*reinterpret_cast<const float4*>(xr0),
           *reinterpret_cast<const float4*>(xr0 + 4), Ah0c0, Am0c0);
    split8(*reinterpret_cast<const float4*>(xr0 + 32),
           *reinterpret_cast<const float4*>(xr0 + 36), Ah0c1, Am0c1);
    split8(*reinterpret_cast<const float4*>(xr1),
           *reinterpret_cast<const float4*>(xr1 + 4), Ah1c0, Am1c0);
    split8(*reinterpret_cast<const float4*>(xr1 + 32),
           *reinterpret_cast<const float4*>(xr1 + 36), Ah1c1, Am1c1);
  }

  float b1[8], b2[8]; int i1[8];   // [s*4+r]
#pragma unroll
  for (int r = 0; r < 8; ++r) { b1[r] = 3.4e38f; b2[r] = 3.4e38f; i1[r] = 0; }

  bf16x8 Bh0 = F[lane], Bm0 = F[64 + lane], Bh1 = F[128 + lane], Bm1 = F[192 + lane];
  float nv = nrm[row];

#pragma unroll 1
  for (int t = 0; t < 32; ++t) {
    const int tn = (t + 1) & 31;                 // wraparound prefetch
    const bf16x8 nBh0 = F[tn * 256 + lane];
    const bf16x8 nBm0 = F[tn * 256 + 64 + lane];
    const bf16x8 nBh1 = F[tn * 256 + 128 + lane];
    const bf16x8 nBm1 = F[tn * 256 + 192 + lane];
    const float nvn = nrm[tn * 16 + row];

    f32x4 a0 = {0.f, 0.f, 0.f, 0.f}, a1 = {0.f, 0.f, 0.f, 0.f};
    a0 = __builtin_amdgcn_mfma_f32_16x16x32_bf16(Ah0c0, Bh0, a0, 0, 0, 0);
    a1 = __builtin_amdgcn_mfma_f32_16x16x32_bf16(Ah1c0, Bh0, a1, 0, 0, 0);
    a0 = __builtin_amdgcn_mfma_f32_16x16x32_bf16(Ah0c1, Bh1, a0, 0, 0, 0);
    a1 = __builtin_amdgcn_mfma_f32_16x16x32_bf16(Ah1c1, Bh1, a1, 0, 0, 0);
    a0 = __builtin_amdgcn_mfma_f32_16x16x32_bf16(Ah0c0, Bm0, a0, 0, 0, 0);
    a1 = __builtin_amdgcn_mfma_f32_16x16x32_bf16(Ah1c0, Bm0, a1, 0, 0, 0);
    a0 = __builtin_amdgcn_mfma_f32_16x16x32_bf16(Ah0c1, Bm1, a0, 0, 0, 0);
    a1 = __builtin_amdgcn_mfma_f32_16x16x32_bf16(Ah1c1, Bm1, a1, 0, 0, 0);
    a0 = __builtin_amdgcn_mfma_f32_16x16x32_bf16(Am0c0, Bh0, a0, 0, 0, 0);
    a1 = __builtin_amdgcn_mfma_f32_16x16x32_bf16(Am1c0, Bh0, a1, 0, 0, 0);
    a0 = __builtin_amdgcn_mfma_f32_16x16x32_bf16(Am0c1, Bh1, a0, 0, 0, 0);
    a1 = __builtin_amdgcn_mfma_f32_16x16x32_bf16(Am1c1, Bh1, a1, 0, 0, 0);

    const int code = t * 16 + row;
#pragma unroll
    for (int r = 0; r < 4; ++r) {
      const float s0 = fmaf(-2.f, a0[r], nv);
      b2[r] = fminf(b2[r], fmaxf(b1[r], s0));
      if (s0 < b1[r]) { b1[r] = s0; i1[r] = code; }
      const float s1 = fmaf(-2.f, a1[r], nv);
      b2[4 + r] = fminf(b2[4 + r], fmaxf(b1[4 + r], s1));
      if (s1 < b1[4 + r]) { b1[4 + r] = s1; i1[4 + r] = code; }
    }
    Bh0 = nBh0; Bm0 = nBm0; Bh1 = nBh1; Bm1 = nBm1; nv = nvn;
  }

  // Butterfly merge across the 16 rows (disjoint code subsets -> exact
  // 1st/2nd of union; ties -> gap 0 -> flagged).
#pragma unroll
  for (int m = 1; m < 16; m <<= 1) {
#pragma unroll
    for (int r = 0; r < 8; ++r) {
      const float o1 = __shfl_xor(b1[r], m, 64);
      const int   oi = __shfl_xor(i1[r], m, 64);
      const float o2 = __shfl_xor(b2[r], m, 64);
      if (o1 < b1[r]) { b2[r] = fminf(b1[r], o2); b1[r] = o1; i1[r] = oi; }
      else            { b2[r] = fminf(b2[r], o1); }
    }
  }

  // Id writes + compact flag list (one atomic per wave).
  unsigned m32 = 0;
  if (row == 0) {   // lanes 0,16,32,48: each owns 8 queries (2 sets x 4 regs)
#pragma unroll
    for (int r = 0; r < 8; ++r) {
      const int qoff = (r >> 2) * 16 + kg * 4 + (r & 3);
      idf[qbase + qoff] = (float)i1[r];
      if (b2[r] - b1[r] < GUARD) m32 |= 1u << qoff;
    }
  }
  m32 |= __shfl_xor((int)m32, 16, 64);
  m32 |= __shfl_xor((int)m32, 32, 64);
  if (lane == 0 && m32) {
    int base = atomicAdd(cnt, __popc(m32));
    while (m32) {
      const int b = __ffs(m32) - 1;
      m32 &= m32 - 1;
      list[base++] = qbase + b;
    }
  }
}

// ---------------------------------------------------------------------------
// Fallback: exact fp32 rescore of listed queries — one wave per query,
// 8 independent group chains (ILP), float4 codebook loads. Per-code numerics
// identical to rounds 1-6: fma chain d ascending, score=fmaf(-2,dot,nrm),
// strict <, ascending-k visit, index tie-break in reduce.
// ---------------------------------------------------------------------------
__global__ __launch_bounds__(256, 2) void vq_fallback_kernel(
    const float* __restrict__ x, const float* __restrict__ et,
    const float* __restrict__ nrm, const int* __restrict__ cnt,
    const int* __restrict__ list, float* __restrict__ idf)
{
  const int lane = threadIdx.x & 63;
  const int wid  = blockIdx.x * 4 + (threadIdx.x >> 6);
  const int nw   = gridDim.x * 4;
  const int n = cnt[0];
  for (int i = wid; i < n; i += nw) {
    const int q = list[i];
    float xv[D];
    {
      const float4* xr = reinterpret_cast<const float4*>(x + (size_t)q * D);
#pragma unroll
      for (int j = 0; j < D / 4; ++j) {
        const float4 t = xr[j];
        xv[4*j] = t.x; xv[4*j+1] = t.y; xv[4*j+2] = t.z; xv[4*j+3] = t.w;
      }
    }
    float a[8];
#pragma unroll
    for (int g = 0; g < 8; ++g) a[g] = 0.f;
#pragma unroll
    for (int dq = 0; dq < D / 4; ++dq) {
#pragma unroll
      for (int g = 0; g < 8; ++g) {   // 8 independent chains, d ascending each
        const float4 ev = *reinterpret_cast<const float4*>(
            et + (size_t)(g * 64 + lane) * D + dq * 4);
        a[g] = fmaf(xv[4*dq+0], ev.x, a[g]);
        a[g] = fmaf(xv[4*dq+1], ev.y, a[g]);
        a[g] = fmaf(xv[4*dq+2], ev.z, a[g]);
        a[g] = fmaf(xv[4*dq+3], ev.w, a[g]);
      }
    }
    float best = 3.4e38f; int bid = 0;
#pragma unroll
    for (int g = 0; g < 8; ++g) {     // ascending k per lane
      const int k = g * 64 + lane;
      const float s = fmaf(-2.f, a[g], nrm[k]);
      if (s < best) { best = s; bid = k; }
    }
#pragma unroll
    for (int off = 32; off > 0; off >>= 1) {
      const float s2 = __shfl_down(best, off, 64);
      const int   b2 = __shfl_down(bid, off, 64);
      if (s2 < best || (s2 == best && b2 < bid)) { best = s2; bid = b2; }
    }
    if (lane == 0) idf[q] = (float)bid;
  }
}

// ---------------------------------------------------------------------------
// Gather: q = et[id] (exact fp32 rows), write q_st, diff partials.
// ---------------------------------------------------------------------------
__global__ __launch_bounds__(256) void vq_gather_kernel(
    const float* __restrict__ x, const float* __restrict__ et,
    const float* __restrict__ idf, float* __restrict__ q,
    float* __restrict__ partial)
{
  const int tid = blockIdx.x * 256 + threadIdx.x;
  const int stride = gridDim.x * 256;
  float acc = 0.f;
  for (int idx = tid; idx < N_VEC * (D / 4); idx += stride) {
    const int v = idx >> 4;
    const int d4 = idx & 15;
    const int id = (int)idf[v];
    const float4 xv = reinterpret_cast<const float4*>(x)[idx];
    const float4 ev = reinterpret_cast<const float4*>(et)[(id << 4) + d4];
    const float e0 = ev.x - xv.x, e1 = ev.y - xv.y, e2 = ev.z - xv.z, e3 = ev.w - xv.w;
    acc += (e0 * e0 + e1 * e1) + (e2 * e2 + e3 * e3);
    reinterpret_cast<float4*>(q)[idx] = ev;
  }
  acc += __shfl_down(acc, 32, 64);
  acc += __shfl_down(acc, 16, 64);
  acc += __shfl_down(acc, 8, 64);
  acc += __shfl_down(acc, 4, 64);
  acc += __shfl_down(acc, 2, 64);
  acc += __shfl_down(acc, 1, 64);
  __shared__ float sred[4];
  if ((threadIdx.x & 63) == 0) sred[threadIdx.x >> 6] = acc;
  __syncthreads();
  if (threadIdx.x == 0)
    partial[blockIdx.x] = (sred[0] + sred[1]) + (sred[2] + sred[3]);
}

__global__ __launch_bounds__(256) void vq_finalize_kernel(
    const float* __restrict__ partial, float* __restrict__ out)
{
  float acc = 0.f;
  for (int i = threadIdx.x; i < NB_GATHER; i += 256) acc += partial[i];
  acc += __shfl_down(acc, 32, 64);
  acc += __shfl_down(acc, 16, 64);
  acc += __shfl_down(acc, 8, 64);
  acc += __shfl_down(acc, 4, 64);
  acc += __shfl_down(acc, 2, 64);
  acc += __shfl_down(acc, 1, 64);
  __shared__ float sred[4];
  if ((threadIdx.x & 63) == 0) sred[threadIdx.x >> 6] = acc;
  __syncthreads();
  if (threadIdx.x == 0)
    out[0] = ((sred[0] + sred[1]) + (sred[2] + sred[3])) * (1.0f / (float)(N_VEC * D));
}

extern "C" void kernel_launch(void* const* d_in, const int* in_sizes, int n_in,
                              void* d_out, int out_size, void* d_ws, size_t ws_size,
                              hipStream_t stream) {
  const float* x = (const float*)d_in[0];
  const float* embed = (const float*)d_in[1];
  float* out = (float*)d_out;
  float* q    = out;                 // [0, 8388608): q_st
  float* diff = out + 8388608;       // commitment loss scalar
  float* idf  = out + 8388609;       // emd_id as float [131072]

  float* ws = (float*)d_ws;          // layout (float idx):
  float* et      = ws;               // [0, 32768)      fp32 codebook rows, 128 KB
  float* nrm     = ws + 32768;       // [32768, 33280)  code norms
  float* partial = ws + 33280;       // [33280, 35328)  diff partials
  int*   cnt     = (int*)(ws + 35328);        // flag counter
  int*   list    = (int*)(ws + 35336);        // flagged query indices (<=512 KB)
  bf16x8* F = (bf16x8*)(ws + 35336 + N_VEC);  // 128 KB packed hi/mid B-frags

  vq_prep_kernel<<<40, 64, 0, stream>>>(embed, et, nrm, F, cnt);
  vq_coarse_kernel<<<N_VEC / 128, 256, 0, stream>>>(x, F, nrm, idf, cnt, list);
  vq_fallback_kernel<<<512, 256, 0, stream>>>(x, et, nrm, cnt, list, idf);
  vq_gather_kernel<<<NB_GATHER, 256, 0, stream>>>(x, et, idf, q, partial);
  vq_finalize_kernel<<<1, 256, 0, stream>>>(partial, diff);
}

// Round 8
// 86.497 us; speedup vs baseline: 1.8682x; 1.8682x over previous
//
#include <hip/hip_runtime.h>

// Problem constants: x [32,64,64,64] f32, embed [64,512] f32.
#define N_VEC 131072
#define D 64
#define K 512
#define GUARD 0.05f      // >= 3.8x the derived 2*eps coarse-error requirement
#define NB_GATHER 2048
#define FB_Q 16          // flagged queries per fallback block

typedef __attribute__((ext_vector_type(8))) short bf16x8;  // 8 bf16 = 4 VGPR
typedef __attribute__((ext_vector_type(4))) float f32x4;

static __device__ __forceinline__ short f2bf(float f) {   // RNE
  unsigned u = __builtin_bit_cast(unsigned, f);
  u += 0x7fffu + ((u >> 16) & 1u);
  return (short)(u >> 16);
}
static __device__ __forceinline__ float bf2f(short h) {
  unsigned u = ((unsigned)(unsigned short)h) << 16;
  return __builtin_bit_cast(float, u);
}
static __device__ __forceinline__ void split8(const float4 f0, const float4 f1,
                                              bf16x8& h, bf16x8& m) {
  const float v[8] = {f0.x, f0.y, f0.z, f0.w, f1.x, f1.y, f1.z, f1.w};
#pragma unroll
  for (int j = 0; j < 8; ++j) {
    const short hh = f2bf(v[j]);
    h[j] = hh;
    m[j] = f2bf(v[j] - bf2f(hh));
  }
}

// ---------------------------------------------------------------------------
// Prep (grid 40 x 64):
//   blocks 0-31:  pack codebook hi/mid bf16 B-fragments (tile b) into F in
//                 MFMA fragment order: F[t*256 + c*128 + s*64 + lane].
//   blocks 32-39: et[k][d] fp32 transpose + nrm (fma order d ascending, same
//                 as rounds 1-7 -> bit-identical) + flag-counter zeroing.
// ---------------------------------------------------------------------------
__global__ __launch_bounds__(64) void vq_prep_kernel(
    const float* __restrict__ embed, float* __restrict__ et,
    float* __restrict__ nrm, bf16x8* __restrict__ F, int* __restrict__ cnt)
{
  const int b = blockIdx.x;
  const int lane = threadIdx.x;
  if (b < 32) {
    const int row = lane & 15;   // code within tile
    const int kg  = lane >> 4;   // dim-group
    const int code = b * 16 + row;
#pragma unroll
    for (int c = 0; c < 2; ++c) {
      bf16x8 h, m;
#pragma unroll
      for (int j = 0; j < 8; ++j) {
        const int d = kg * 8 + c * 32 + j;
        const float e = embed[d * K + code];
        const short hh = f2bf(e);
        h[j] = hh;
        m[j] = f2bf(e - bf2f(hh));
      }
      F[b * 256 + c * 128 + 0  + lane] = h;
      F[b * 256 + c * 128 + 64 + lane] = m;
    }
  } else {
    if (b == 32 && lane == 0) cnt[0] = 0;
    const int code = (b - 32) * 64 + lane;     // 0..511
    float s = 0.f;
#pragma unroll
    for (int d = 0; d < D; ++d) {
      const float e = embed[d * K + code];
      et[code * D + d] = e;
      s = fmaf(e, e, s);
    }
    nrm[code] = s;
  }
}

// ---------------------------------------------------------------------------
// Coarse: wave = 32 queries (two 16-row A-sets, hi/mid bf16), streams 32
// code-tiles of 16 via pre-packed B-frags. 12 MFMA/tile. Per lane: 8
// best/2nd/idx triples. gap<GUARD -> query index appended to compact list.
// Scoring numerics identical to rounds 5-7 (passed).
// ---------------------------------------------------------------------------
__global__ __launch_bounds__(256, 4) void vq_coarse_kernel(
    const float* __restrict__ x, const bf16x8* __restrict__ F,
    const float* __restrict__ nrm, float* __restrict__ idf,
    int* __restrict__ cnt, int* __restrict__ list)
{
  const int tid  = threadIdx.x;
  const int lane = tid & 63;
  const int wid  = blockIdx.x * 4 + (tid >> 6);
  const int qbase = wid * 32;
  const int row = lane & 15;
  const int kg  = lane >> 4;

  // Build A fragments (2 query-sets x 2 K-chunks, hi+mid).
  bf16x8 Ah0c0, Ah0c1, Ah1c0, Ah1c1, Am0c0, Am0c1, Am1c0, Am1c1;
  {
    const float* xr0 = x + (size_t)(qbase + row) * D + kg * 8;
    const float* xr1 = x + (size_t)(qbase + 16 + row) * D + kg * 8;
    split8(*reinterpret_cast<const float4*>(xr0),
           *reinterpret_cast<const float4*>(xr0 + 4), Ah0c0, Am0c0);
    split8(*reinterpret_cast<const float4*>(xr0 + 32),
           *reinterpret_cast<const float4*>(xr0 + 36), Ah0c1, Am0c1);
    split8(*reinterpret_cast<const float4*>(xr1),
           *reinterpret_cast<const float4*>(xr1 + 4), Ah1c0, Am1c0);
    split8(*reinterpret_cast<const float4*>(xr1 + 32),
           *reinterpret_cast<const float4*>(xr1 + 36), Ah1c1, Am1c1);
  }

  float b1[8], b2[8]; int i1[8];   // [s*4+r]
#pragma unroll
  for (int r = 0; r < 8; ++r) { b1[r] = 3.4e38f; b2[r] = 3.4e38f; i1[r] = 0; }

  bf16x8 Bh0 = F[lane], Bm0 = F[64 + lane], Bh1 = F[128 + lane], Bm1 = F[192 + lane];
  float nv = nrm[row];

#pragma unroll 1
  for (int t = 0; t < 32; ++t) {
    const int tn = (t + 1) & 31;                 // wraparound prefetch
    const bf16x8 nBh0 = F[tn * 256 + lane];
    const bf16x8 nBm0 = F[tn * 256 + 64 + lane];
    const bf16x8 nBh1 = F[tn * 256 + 128 + lane];
    const bf16x8 nBm1 = F[tn * 256 + 192 + lane];
    const float nvn = nrm[tn * 16 + row];

    f32x4 a0 = {0.f, 0.f, 0.f, 0.f}, a1 = {0.f, 0.f, 0.f, 0.f};
    a0 = __builtin_amdgcn_mfma_f32_16x16x32_bf16(Ah0c0, Bh0, a0, 0, 0, 0);
    a1 = __builtin_amdgcn_mfma_f32_16x16x32_bf16(Ah1c0, Bh0, a1, 0, 0, 0);
    a0 = __builtin_amdgcn_mfma_f32_16x16x32_bf16(Ah0c1, Bh1, a0, 0, 0, 0);
    a1 = __builtin_amdgcn_mfma_f32_16x16x32_bf16(Ah1c1, Bh1, a1, 0, 0, 0);
    a0 = __builtin_amdgcn_mfma_f32_16x16x32_bf16(Ah0c0, Bm0, a0, 0, 0, 0);
    a1 = __builtin_amdgcn_mfma_f32_16x16x32_bf16(Ah1c0, Bm0, a1, 0, 0, 0);
    a0 = __builtin_amdgcn_mfma_f32_16x16x32_bf16(Ah0c1, Bm1, a0, 0, 0, 0);
    a1 = __builtin_amdgcn_mfma_f32_16x16x32_bf16(Ah1c1, Bm1, a1, 0, 0, 0);
    a0 = __builtin_amdgcn_mfma_f32_16x16x32_bf16(Am0c0, Bh0, a0, 0, 0, 0);
    a1 = __builtin_amdgcn_mfma_f32_16x16x32_bf16(Am1c0, Bh0, a1, 0, 0, 0);
    a0 = __builtin_amdgcn_mfma_f32_16x16x32_bf16(Am0c1, Bh1, a0, 0, 0, 0);
    a1 = __builtin_amdgcn_mfma_f32_16x16x32_bf16(Am1c1, Bh1, a1, 0, 0, 0);

    const int code = t * 16 + row;
#pragma unroll
    for (int r = 0; r < 4; ++r) {
      const float s0 = fmaf(-2.f, a0[r], nv);
      b2[r] = fminf(b2[r], fmaxf(b1[r], s0));
      if (s0 < b1[r]) { b1[r] = s0; i1[r] = code; }
      const float s1 = fmaf(-2.f, a1[r], nv);
      b2[4 + r] = fminf(b2[4 + r], fmaxf(b1[4 + r], s1));
      if (s1 < b1[4 + r]) { b1[4 + r] = s1; i1[4 + r] = code; }
    }
    Bh0 = nBh0; Bm0 = nBm0; Bh1 = nBh1; Bm1 = nBm1; nv = nvn;
  }

  // Butterfly merge across the 16 rows (disjoint code subsets -> exact
  // 1st/2nd of union; ties -> gap 0 -> flagged).
#pragma unroll
  for (int m = 1; m < 16; m <<= 1) {
#pragma unroll
    for (int r = 0; r < 8; ++r) {
      const float o1 = __shfl_xor(b1[r], m, 64);
      const int   oi = __shfl_xor(i1[r], m, 64);
      const float o2 = __shfl_xor(b2[r], m, 64);
      if (o1 < b1[r]) { b2[r] = fminf(b1[r], o2); b1[r] = o1; i1[r] = oi; }
      else            { b2[r] = fminf(b2[r], o1); }
    }
  }

  // Id writes + compact flag list (one atomic per wave).
  unsigned m32 = 0;
  if (row == 0) {   // lanes 0,16,32,48: each owns 8 queries (2 sets x 4 regs)
#pragma unroll
    for (int r = 0; r < 8; ++r) {
      const int qoff = (r >> 2) * 16 + kg * 4 + (r & 3);
      idf[qbase + qoff] = (float)i1[r];
      if (b2[r] - b1[r] < GUARD) m32 |= 1u << qoff;
    }
  }
  m32 |= __shfl_xor((int)m32, 16, 64);
  m32 |= __shfl_xor((int)m32, 32, 64);
  if (lane == 0 && m32) {
    int base = atomicAdd(cnt, __popc(m32));
    while (m32) {
      const int b = __ffs(m32) - 1;
      m32 &= m32 - 1;
      list[base++] = qbase + b;
    }
  }
}

// ---------------------------------------------------------------------------
// Fallback v3: exact fp32 rescore, 16 flagged queries per 256-thread block.
// x rows staged in LDS (broadcast b128 reads); lane = code, e read from the
// ORIGINAL embed [d][K] layout -> fully coalesced 256-B lines, L2-hot.
// Per-code numerics identical to rounds 1-7's exact path: fma chain d
// ascending, score=fmaf(-2,dot,nrm), strict <, ascending-k visit per lane,
// min-index tie-break in wave reduce, ascending-wave merge.
// ---------------------------------------------------------------------------
__global__ __launch_bounds__(256) void vq_fallback_kernel(
    const float* __restrict__ x, const float* __restrict__ embed,
    const float* __restrict__ nrm, const int* __restrict__ cnt,
    const int* __restrict__ list, float* __restrict__ idf)
{
  __shared__ float x_lds[FB_Q * D];   // 4 KB
  __shared__ int   s_qidx[FB_Q];
  __shared__ float s_best[4][FB_Q];
  __shared__ int   s_bid[4][FB_Q];
  const int tid  = threadIdx.x;
  const int lane = tid & 63;
  const int wv   = tid >> 6;          // 0..3: codes wv*128 + {lane, lane+64}
  const int n = cnt[0];

  for (int qb = blockIdx.x * FB_Q; qb < n; qb += gridDim.x * FB_Q) {
    __syncthreads();   // previous batch's epilogue reads done before overwrite
    if (tid < FB_Q) {
      const int idx = qb + tid;
      s_qidx[tid] = list[idx < n ? idx : qb];  // pad with first-of-batch (dup-safe)
    }
    __syncthreads();
    {  // stage x rows: 16 q x 16 float4 = 256 loads, 1 per thread
      const int qj = tid >> 4, dq = tid & 15;
      *reinterpret_cast<float4*>(&x_lds[qj * D + dq * 4]) =
          *reinterpret_cast<const float4*>(x + (size_t)s_qidx[qj] * D + dq * 4);
    }
    __syncthreads();

    const int c0 = wv * 128 + lane;
    const int c1 = c0 + 64;
    float a0[FB_Q], a1[FB_Q];
#pragma unroll
    for (int i = 0; i < FB_Q; ++i) { a0[i] = 0.f; a1[i] = 0.f; }

#pragma unroll 4
    for (int ch = 0; ch < 16; ++ch) {   // 4 dims per chunk, d ascending
      const int d0 = ch * 4;
      const float e00 = embed[(d0 + 0) * K + c0];
      const float e01 = embed[(d0 + 0) * K + c1];
      const float e10 = embed[(d0 + 1) * K + c0];
      const float e11 = embed[(d0 + 1) * K + c1];
      const float e20 = embed[(d0 + 2) * K + c0];
      const float e21 = embed[(d0 + 2) * K + c1];
      const float e30 = embed[(d0 + 3) * K + c0];
      const float e31 = embed[(d0 + 3) * K + c1];
#pragma unroll
      for (int i = 0; i < FB_Q; ++i) {
        const float4 xv = *reinterpret_cast<const float4*>(&x_lds[i * D + d0]);
        a0[i] = fmaf(xv.x, e00, a0[i]);
        a0[i] = fmaf(xv.y, e10, a0[i]);
        a0[i] = fmaf(xv.z, e20, a0[i]);
        a0[i] = fmaf(xv.w, e30, a0[i]);
        a1[i] = fmaf(xv.x, e01, a1[i]);
        a1[i] = fmaf(xv.y, e11, a1[i]);
        a1[i] = fmaf(xv.z, e21, a1[i]);
        a1[i] = fmaf(xv.w, e31, a1[i]);
      }
    }

    const float nr0 = nrm[c0], nr1 = nrm[c1];
#pragma unroll
    for (int i = 0; i < FB_Q; ++i) {
      float best; int bid;
      const float s0 = fmaf(-2.f, a0[i], nr0);
      best = s0; bid = c0;                      // c0 < c1, visited first
      const float s1 = fmaf(-2.f, a1[i], nr1);
      if (s1 < best) { best = s1; bid = c1; }
#pragma unroll
      for (int off = 32; off > 0; off >>= 1) {
        const float s2 = __shfl_down(best, off, 64);
        const int   b2 = __shfl_down(bid, off, 64);
        if (s2 < best || (s2 == best && b2 < bid)) { best = s2; bid = b2; }
      }
      if (lane == 0) { s_best[wv][i] = best; s_bid[wv][i] = bid; }
    }
    __syncthreads();
    if (tid < FB_Q) {   // merge 4 waves, ascending wv = ascending code range
      float best = s_best[0][tid]; int bid = s_bid[0][tid];
#pragma unroll
      for (int w = 1; w < 4; ++w) {
        const float s = s_best[w][tid];
        if (s < best) { best = s; bid = s_bid[w][tid]; }  // tie keeps lower k
      }
      idf[s_qidx[tid]] = (float)bid;
    }
  }
}

// ---------------------------------------------------------------------------
// Gather: q = et[id] (exact fp32 rows), write q_st, diff partials.
// ---------------------------------------------------------------------------
__global__ __launch_bounds__(256) void vq_gather_kernel(
    const float* __restrict__ x, const float* __restrict__ et,
    const float* __restrict__ idf, float* __restrict__ q,
    float* __restrict__ partial)
{
  const int tid = blockIdx.x * 256 + threadIdx.x;
  const int stride = gridDim.x * 256;
  float acc = 0.f;
  for (int idx = tid; idx < N_VEC * (D / 4); idx += stride) {
    const int v = idx >> 4;
    const int d4 = idx & 15;
    const int id = (int)idf[v];
    const float4 xv = reinterpret_cast<const float4*>(x)[idx];
    const float4 ev = reinterpret_cast<const float4*>(et)[(id << 4) + d4];
    const float e0 = ev.x - xv.x, e1 = ev.y - xv.y, e2 = ev.z - xv.z, e3 = ev.w - xv.w;
    acc += (e0 * e0 + e1 * e1) + (e2 * e2 + e3 * e3);
    reinterpret_cast<float4*>(q)[idx] = ev;
  }
  acc += __shfl_down(acc, 32, 64);
  acc += __shfl_down(acc, 16, 64);
  acc += __shfl_down(acc, 8, 64);
  acc += __shfl_down(acc, 4, 64);
  acc += __shfl_down(acc, 2, 64);
  acc += __shfl_down(acc, 1, 64);
  __shared__ float sred[4];
  if ((threadIdx.x & 63) == 0) sred[threadIdx.x >> 6] = acc;
  __syncthreads();
  if (threadIdx.x == 0)
    partial[blockIdx.x] = (sred[0] + sred[1]) + (sred[2] + sred[3]);
}

__global__ __launch_bounds__(256) void vq_finalize_kernel(
    const float* __restrict__ partial, float* __restrict__ out)
{
  float acc = 0.f;
  for (int i = threadIdx.x; i < NB_GATHER; i += 256) acc += partial[i];
  acc += __shfl_down(acc, 32, 64);
  acc += __shfl_down(acc, 16, 64);
  acc += __shfl_down(acc, 8, 64);
  acc += __shfl_down(acc, 4, 64);
  acc += __shfl_down(acc, 2, 64);
  acc += __shfl_down(acc, 1, 64);
  __shared__ float sred[4];
  if ((threadIdx.x & 63) == 0) sred[threadIdx.x >> 6] = acc;
  __syncthreads();
  if (threadIdx.x == 0)
    out[0] = ((sred[0] + sred[1]) + (sred[2] + sred[3])) * (1.0f / (float)(N_VEC * D));
}

extern "C" void kernel_launch(void* const* d_in, const int* in_sizes, int n_in,
                              void* d_out, int out_size, void* d_ws, size_t ws_size,
                              hipStream_t stream) {
  const float* x = (const float*)d_in[0];
  const float* embed = (const float*)d_in[1];
  float* out = (float*)d_out;
  float* q    = out;                 // [0, 8388608): q_st
  float* diff = out + 8388608;       // commitment loss scalar
  float* idf  = out + 8388609;       // emd_id as float [131072]

  float* ws = (float*)d_ws;          // layout (float idx):
  float* et      = ws;               // [0, 32768)      fp32 codebook rows, 128 KB
  float* nrm     = ws + 32768;       // [32768, 33280)  code norms
  float* partial = ws + 33280;       // [33280, 35328)  diff partials
  int*   cnt     = (int*)(ws + 35328);        // flag counter
  int*   list    = (int*)(ws + 35336);        // flagged query indices
  bf16x8* F = (bf16x8*)(ws + 35336 + N_VEC);  // 128 KB packed hi/mid B-frags

  vq_prep_kernel<<<40, 64, 0, stream>>>(embed, et, nrm, F, cnt);
  vq_coarse_kernel<<<N_VEC / 128, 256, 0, stream>>>(x, F, nrm, idf, cnt, list);
  vq_fallback_kernel<<<1024, 256, 0, stream>>>(x, embed, nrm, cnt, list, idf);
  vq_gather_kernel<<<NB_GATHER, 256, 0, stream>>>(x, et, idf, q, partial);
  vq_finalize_kernel<<<1, 256, 0, stream>>>(partial, diff);
}

// Round 9
// 84.314 us; speedup vs baseline: 1.9166x; 1.0259x over previous
//
#include <hip/hip_runtime.h>

// Problem constants: x [32,64,64,64] f32, embed [64,512] f32.
#define N_VEC 131072
#define D 64
#define K 512
#define GUARD 0.05f      // >= 3.8x the derived 2*eps coarse-error requirement
#define NB_GATHER 2048
#define FB_Q 16          // flagged queries per fallback block

typedef __attribute__((ext_vector_type(8))) short bf16x8;  // 8 bf16 = 4 VGPR
typedef __attribute__((ext_vector_type(4))) float f32x4;

static __device__ __forceinline__ short f2bf(float f) {   // RNE
  unsigned u = __builtin_bit_cast(unsigned, f);
  u += 0x7fffu + ((u >> 16) & 1u);
  return (short)(u >> 16);
}
static __device__ __forceinline__ float bf2f(short h) {
  unsigned u = ((unsigned)(unsigned short)h) << 16;
  return __builtin_bit_cast(float, u);
}
static __device__ __forceinline__ void split8(const float4 f0, const float4 f1,
                                              bf16x8& h, bf16x8& m) {
  const float v[8] = {f0.x, f0.y, f0.z, f0.w, f1.x, f1.y, f1.z, f1.w};
#pragma unroll
  for (int j = 0; j < 8; ++j) {
    const short hh = f2bf(v[j]);
    h[j] = hh;
    m[j] = f2bf(v[j] - bf2f(hh));
  }
}

// ---------------------------------------------------------------------------
// Prep (grid 40 x 64):
//   blocks 0-31:  pack codebook hi/mid bf16 B-fragments (tile b) into F in
//                 MFMA fragment order: F[t*256 + c*128 + s*64 + lane].
//   blocks 32-39: et[k][d] fp32 transpose + nrm (fma order d ascending, same
//                 as rounds 1-8 -> bit-identical) + flag-counter zeroing.
// ---------------------------------------------------------------------------
__global__ __launch_bounds__(64) void vq_prep_kernel(
    const float* __restrict__ embed, float* __restrict__ et,
    float* __restrict__ nrm, bf16x8* __restrict__ F, int* __restrict__ cnt)
{
  const int b = blockIdx.x;
  const int lane = threadIdx.x;
  if (b < 32) {
    const int row = lane & 15;   // code within tile
    const int kg  = lane >> 4;   // dim-group
    const int code = b * 16 + row;
#pragma unroll
    for (int c = 0; c < 2; ++c) {
      bf16x8 h, m;
#pragma unroll
      for (int j = 0; j < 8; ++j) {
        const int d = kg * 8 + c * 32 + j;
        const float e = embed[d * K + code];
        const short hh = f2bf(e);
        h[j] = hh;
        m[j] = f2bf(e - bf2f(hh));
      }
      F[b * 256 + c * 128 + 0  + lane] = h;
      F[b * 256 + c * 128 + 64 + lane] = m;
    }
  } else {
    if (b == 32 && lane == 0) cnt[0] = 0;
    const int code = (b - 32) * 64 + lane;     // 0..511
    float s = 0.f;
#pragma unroll
    for (int d = 0; d < D; ++d) {
      const float e = embed[d * K + code];
      et[code * D + d] = e;
      s = fmaf(e, e, s);
    }
    nrm[code] = s;
  }
}

// ---------------------------------------------------------------------------
// Coarse v3: wave = 32 queries; 32 code-tiles of 16. B-frags staged in LDS,
// DOUBLE-BUFFERED and SHARED by the block's 4 waves (4 KB/tile staged once:
// thread = one float4; next-tile global load issued at iteration top, LDS
// write just before the single end-of-iteration barrier -> L2 latency hides
// under the tile's 12 MFMA + scoring). Affine src pointers (no (t+1)&31
// remul). Scoring: b2 via v_med3_f32 (value-identical to fmin/fmax pair).
// All operand bytes and score numerics identical to rounds 5-8 (passed).
// ---------------------------------------------------------------------------
__global__ __launch_bounds__(256, 4) void vq_coarse_kernel(
    const float* __restrict__ x, const bf16x8* __restrict__ F,
    const float* __restrict__ nrm, float* __restrict__ idf,
    int* __restrict__ cnt, int* __restrict__ list)
{
  __shared__ bf16x8 lb[2][256];      // 8 KB: double-buffered B tile
  const int tid  = threadIdx.x;
  const int lane = tid & 63;
  const int wid  = blockIdx.x * 4 + (tid >> 6);
  const int qbase = wid * 32;
  const int row = lane & 15;
  const int kg  = lane >> 4;

  // Build A fragments (2 query-sets x 2 K-chunks, hi+mid).
  bf16x8 Ah0c0, Ah0c1, Ah1c0, Ah1c1, Am0c0, Am0c1, Am1c0, Am1c1;
  {
    const float* xr0 = x + (size_t)(qbase + row) * D + kg * 8;
    const float* xr1 = x + (size_t)(qbase + 16 + row) * D + kg * 8;
    split8(*reinterpret_cast<const float4*>(xr0),
           *reinterpret_cast<const float4*>(xr0 + 4), Ah0c0, Am0c0);
    split8(*reinterpret_cast<const float4*>(xr0 + 32),
           *reinterpret_cast<const float4*>(xr0 + 36), Ah0c1, Am0c1);
    split8(*reinterpret_cast<const float4*>(xr1),
           *reinterpret_cast<const float4*>(xr1 + 4), Ah1c0, Am1c0);
    split8(*reinterpret_cast<const float4*>(xr1 + 32),
           *reinterpret_cast<const float4*>(xr1 + 36), Ah1c1, Am1c1);
  }

  float b1[8], b2[8]; int i1[8];   // [s*4+r]
#pragma unroll
  for (int r = 0; r < 8; ++r) { b1[r] = 3.4e38f; b2[r] = 3.4e38f; i1[r] = 0; }

  // Stage tile 0; affine running pointers for tile t+1.
  reinterpret_cast<float4*>(lb[0])[tid] = reinterpret_cast<const float4*>(F)[tid];
  const float4* fs = reinterpret_cast<const float4*>(F) + 256 + tid;
  const float* np = nrm + 16 + row;
  float nv = nrm[row];
  __syncthreads();

#pragma unroll 1
  for (int t = 0; t < 32; ++t) {
    float4 f4; float nvn;
    if (t < 31) {                      // issue next-tile loads (L2-hot)
      f4 = *fs; fs += 256;
      nvn = *np; np += 16;
    }

    const bf16x8* lbc = lb[t & 1];
    const bf16x8 Bh0 = lbc[lane];
    const bf16x8 Bm0 = lbc[64 + lane];
    const bf16x8 Bh1 = lbc[128 + lane];
    const bf16x8 Bm1 = lbc[192 + lane];

    f32x4 a0 = {0.f, 0.f, 0.f, 0.f}, a1 = {0.f, 0.f, 0.f, 0.f};
    a0 = __builtin_amdgcn_mfma_f32_16x16x32_bf16(Ah0c0, Bh0, a0, 0, 0, 0);
    a1 = __builtin_amdgcn_mfma_f32_16x16x32_bf16(Ah1c0, Bh0, a1, 0, 0, 0);
    a0 = __builtin_amdgcn_mfma_f32_16x16x32_bf16(Ah0c1, Bh1, a0, 0, 0, 0);
    a1 = __builtin_amdgcn_mfma_f32_16x16x32_bf16(Ah1c1, Bh1, a1, 0, 0, 0);
    a0 = __builtin_amdgcn_mfma_f32_16x16x32_bf16(Ah0c0, Bm0, a0, 0, 0, 0);
    a1 = __builtin_amdgcn_mfma_f32_16x16x32_bf16(Ah1c0, Bm0, a1, 0, 0, 0);
    a0 = __builtin_amdgcn_mfma_f32_16x16x32_bf16(Ah0c1, Bm1, a0, 0, 0, 0);
    a1 = __builtin_amdgcn_mfma_f32_16x16x32_bf16(Ah1c1, Bm1, a1, 0, 0, 0);
    a0 = __builtin_amdgcn_mfma_f32_16x16x32_bf16(Am0c0, Bh0, a0, 0, 0, 0);
    a1 = __builtin_amdgcn_mfma_f32_16x16x32_bf16(Am1c0, Bh0, a1, 0, 0, 0);
    a0 = __builtin_amdgcn_mfma_f32_16x16x32_bf16(Am0c1, Bh1, a0, 0, 0, 0);
    a1 = __builtin_amdgcn_mfma_f32_16x16x32_bf16(Am1c1, Bh1, a1, 0, 0, 0);

    const int code = t * 16 + row;
#pragma unroll
    for (int r = 0; r < 4; ++r) {
      const float s0 = fmaf(-2.f, a0[r], nv);
      b2[r] = __builtin_amdgcn_fmed3f(s0, b1[r], b2[r]);   // == min(b2,max(b1,s0))
      if (s0 < b1[r]) { b1[r] = s0; i1[r] = code; }
      const float s1 = fmaf(-2.f, a1[r], nv);
      b2[4 + r] = __builtin_amdgcn_fmed3f(s1, b1[4 + r], b2[4 + r]);
      if (s1 < b1[4 + r]) { b1[4 + r] = s1; i1[4 + r] = code; }
    }

    if (t < 31) {   // write next tile (nobody reads lb[(t+1)&1] this iter)
      reinterpret_cast<float4*>(lb[(t + 1) & 1])[tid] = f4;
      nv = nvn;
    }
    __syncthreads();   // readers of lb[t&1] done before it's overwritten at t+1
  }

  // Butterfly merge across the 16 rows (disjoint code subsets -> exact
  // 1st/2nd of union; ties -> gap 0 -> flagged).
#pragma unroll
  for (int m = 1; m < 16; m <<= 1) {
#pragma unroll
    for (int r = 0; r < 8; ++r) {
      const float o1 = __shfl_xor(b1[r], m, 64);
      const int   oi = __shfl_xor(i1[r], m, 64);
      const float o2 = __shfl_xor(b2[r], m, 64);
      if (o1 < b1[r]) { b2[r] = fminf(b1[r], o2); b1[r] = o1; i1[r] = oi; }
      else            { b2[r] = fminf(b2[r], o1); }
    }
  }

  // Id writes + compact flag list (one atomic per wave).
  unsigned m32 = 0;
  if (row == 0) {   // lanes 0,16,32,48: each owns 8 queries (2 sets x 4 regs)
#pragma unroll
    for (int r = 0; r < 8; ++r) {
      const int qoff = (r >> 2) * 16 + kg * 4 + (r & 3);
      idf[qbase + qoff] = (float)i1[r];
      if (b2[r] - b1[r] < GUARD) m32 |= 1u << qoff;
    }
  }
  m32 |= __shfl_xor((int)m32, 16, 64);
  m32 |= __shfl_xor((int)m32, 32, 64);
  if (lane == 0 && m32) {
    int base = atomicAdd(cnt, __popc(m32));
    while (m32) {
      const int b = __ffs(m32) - 1;
      m32 &= m32 - 1;
      list[base++] = qbase + b;
    }
  }
}

// ---------------------------------------------------------------------------
// Fallback v3 (unchanged, proven): exact fp32 rescore, 16 flagged queries per
// block; lane = code, coalesced embed [d][K] reads; numerics bit-identical to
// the round-1 exact path.
// ---------------------------------------------------------------------------
__global__ __launch_bounds__(256) void vq_fallback_kernel(
    const float* __restrict__ x, const float* __restrict__ embed,
    const float* __restrict__ nrm, const int* __restrict__ cnt,
    const int* __restrict__ list, float* __restrict__ idf)
{
  __shared__ float x_lds[FB_Q * D];   // 4 KB
  __shared__ int   s_qidx[FB_Q];
  __shared__ float s_best[4][FB_Q];
  __shared__ int   s_bid[4][FB_Q];
  const int tid  = threadIdx.x;
  const int lane = tid & 63;
  const int wv   = tid >> 6;          // 0..3: codes wv*128 + {lane, lane+64}
  const int n = cnt[0];

  for (int qb = blockIdx.x * FB_Q; qb < n; qb += gridDim.x * FB_Q) {
    __syncthreads();   // previous batch's epilogue reads done before overwrite
    if (tid < FB_Q) {
      const int idx = qb + tid;
      s_qidx[tid] = list[idx < n ? idx : qb];  // pad with first-of-batch (dup-safe)
    }
    __syncthreads();
    {  // stage x rows: 16 q x 16 float4 = 256 loads, 1 per thread
      const int qj = tid >> 4, dq = tid & 15;
      *reinterpret_cast<float4*>(&x_lds[qj * D + dq * 4]) =
          *reinterpret_cast<const float4*>(x + (size_t)s_qidx[qj] * D + dq * 4);
    }
    __syncthreads();

    const int c0 = wv * 128 + lane;
    const int c1 = c0 + 64;
    float a0[FB_Q], a1[FB_Q];
#pragma unroll
    for (int i = 0; i < FB_Q; ++i) { a0[i] = 0.f; a1[i] = 0.f; }

#pragma unroll 4
    for (int ch = 0; ch < 16; ++ch) {   // 4 dims per chunk, d ascending
      const int d0 = ch * 4;
      const float e00 = embed[(d0 + 0) * K + c0];
      const float e01 = embed[(d0 + 0) * K + c1];
      const float e10 = embed[(d0 + 1) * K + c0];
      const float e11 = embed[(d0 + 1) * K + c1];
      const float e20 = embed[(d0 + 2) * K + c0];
      const float e21 = embed[(d0 + 2) * K + c1];
      const float e30 = embed[(d0 + 3) * K + c0];
      const float e31 = embed[(d0 + 3) * K + c1];
#pragma unroll
      for (int i = 0; i < FB_Q; ++i) {
        const float4 xv = *reinterpret_cast<const float4*>(&x_lds[i * D + d0]);
        a0[i] = fmaf(xv.x, e00, a0[i]);
        a0[i] = fmaf(xv.y, e10, a0[i]);
        a0[i] = fmaf(xv.z, e20, a0[i]);
        a0[i] = fmaf(xv.w, e30, a0[i]);
        a1[i] = fmaf(xv.x, e01, a1[i]);
        a1[i] = fmaf(xv.y, e11, a1[i]);
        a1[i] = fmaf(xv.z, e21, a1[i]);
        a1[i] = fmaf(xv.w, e31, a1[i]);
      }
    }

    const float nr0 = nrm[c0], nr1 = nrm[c1];
#pragma unroll
    for (int i = 0; i < FB_Q; ++i) {
      float best; int bid;
      const float s0 = fmaf(-2.f, a0[i], nr0);
      best = s0; bid = c0;                      // c0 < c1, visited first
      const float s1 = fmaf(-2.f, a1[i], nr1);
      if (s1 < best) { best = s1; bid = c1; }
#pragma unroll
      for (int off = 32; off > 0; off >>= 1) {
        const float s2 = __shfl_down(best, off, 64);
        const int   b2 = __shfl_down(bid, off, 64);
        if (s2 < best || (s2 == best && b2 < bid)) { best = s2; bid = b2; }
      }
      if (lane == 0) { s_best[wv][i] = best; s_bid[wv][i] = bid; }
    }
    __syncthreads();
    if (tid < FB_Q) {   // merge 4 waves, ascending wv = ascending code range
      float best = s_best[0][tid]; int bid = s_bid[0][tid];
#pragma unroll
      for (int w = 1; w < 4; ++w) {
        const float s = s_best[w][tid];
        if (s < best) { best = s; bid = s_bid[w][tid]; }  // tie keeps lower k
      }
      idf[s_qidx[tid]] = (float)bid;
    }
  }
}

// ---------------------------------------------------------------------------
// Gather: q = et[id] (exact fp32 rows), write q_st, diff partials.
// ---------------------------------------------------------------------------
__global__ __launch_bounds__(256) void vq_gather_kernel(
    const float* __restrict__ x, const float* __restrict__ et,
    const float* __restrict__ idf, float* __restrict__ q,
    float* __restrict__ partial)
{
  const int tid = blockIdx.x * 256 + threadIdx.x;
  const int stride = gridDim.x * 256;
  float acc = 0.f;
  for (int idx = tid; idx < N_VEC * (D / 4); idx += stride) {
    const int v = idx >> 4;
    const int d4 = idx & 15;
    const int id = (int)idf[v];
    const float4 xv = reinterpret_cast<const float4*>(x)[idx];
    const float4 ev = reinterpret_cast<const float4*>(et)[(id << 4) + d4];
    const float e0 = ev.x - xv.x, e1 = ev.y - xv.y, e2 = ev.z - xv.z, e3 = ev.w - xv.w;
    acc += (e0 * e0 + e1 * e1) + (e2 * e2 + e3 * e3);
    reinterpret_cast<float4*>(q)[idx] = ev;
  }
  acc += __shfl_down(acc, 32, 64);
  acc += __shfl_down(acc, 16, 64);
  acc += __shfl_down(acc, 8, 64);
  acc += __shfl_down(acc, 4, 64);
  acc += __shfl_down(acc, 2, 64);
  acc += __shfl_down(acc, 1, 64);
  __shared__ float sred[4];
  if ((threadIdx.x & 63) == 0) sred[threadIdx.x >> 6] = acc;
  __syncthreads();
  if (threadIdx.x == 0)
    partial[blockIdx.x] = (sred[0] + sred[1]) + (sred[2] + sred[3]);
}

__global__ __launch_bounds__(256) void vq_finalize_kernel(
    const float* __restrict__ partial, float* __restrict__ out)
{
  float acc = 0.f;
  for (int i = threadIdx.x; i < NB_GATHER; i += 256) acc += partial[i];
  acc += __shfl_down(acc, 32, 64);
  acc += __shfl_down(acc, 16, 64);
  acc += __shfl_down(acc, 8, 64);
  acc += __shfl_down(acc, 4, 64);
  acc += __shfl_down(acc, 2, 64);
  acc += __shfl_down(acc, 1, 64);
  __shared__ float sred[4];
  if ((threadIdx.x & 63) == 0) sred[threadIdx.x >> 6] = acc;
  __syncthreads();
  if (threadIdx.x == 0)
    out[0] = ((sred[0] + sred[1]) + (sred[2] + sred[3])) * (1.0f / (float)(N_VEC * D));
}

extern "C" void kernel_launch(void* const* d_in, const int* in_sizes, int n_in,
                              void* d_out, int out_size, void* d_ws, size_t ws_size,
                              hipStream_t stream) {
  const float* x = (const float*)d_in[0];
  const float* embed = (const float*)d_in[1];
  float* out = (float*)d_out;
  float* q    = out;                 // [0, 8388608): q_st
  float* diff = out + 8388608;       // commitment loss scalar
  float* idf  = out + 8388609;       // emd_id as float [131072]

  float* ws = (float*)d_ws;          // layout (float idx):
  float* et      = ws;               // [0, 32768)      fp32 codebook rows, 128 KB
  float* nrm     = ws + 32768;       // [32768, 33280)  code norms
  float* partial = ws + 33280;       // [33280, 35328)  diff partials
  int*   cnt     = (int*)(ws + 35328);        // flag counter
  int*   list    = (int*)(ws + 35336);        // flagged query indices
  bf16x8* F = (bf16x8*)(ws + 35336 + N_VEC);  // 128 KB packed hi/mid B-frags

  vq_prep_kernel<<<40, 64, 0, stream>>>(embed, et, nrm, F, cnt);
  vq_coarse_kernel<<<N_VEC / 128, 256, 0, stream>>>(x, F, nrm, idf, cnt, list);
  vq_fallback_kernel<<<1024, 256, 0, stream>>>(x, embed, nrm, cnt, list, idf);
  vq_gather_kernel<<<NB_GATHER, 256, 0, stream>>>(x, et, idf, q, partial);
  vq_finalize_kernel<<<1, 256, 0, stream>>>(partial, diff);
}